// Round 7
// baseline (41.670 us; speedup 1.0000x reference)
//
#include <hip/hip_runtime.h>

#define NN   2048
#define EE   65536
#define EDIM 64
#define LL   5
#define TPK2 262144   // total threads in pairs_kernel (256 blocks x 1024)

// Kernel 1: dotsT[l][e] = sum_d edge_attr[e][d] * edge_vector[l][d]  (fp16, transposed)
__global__ __launch_bounds__(256) void dots_kernel(
    const float* __restrict__ edge_attr,
    const float* __restrict__ edge_vector,
    _Float16* __restrict__ dotsT) {
  const int lane = threadIdx.x & 63;
  const int wib  = threadIdx.x >> 6;   // wave in block: 0..3
  const int dg   = lane & 15;          // d-group: 4 floats each
  const int es   = lane >> 4;          // edge within wave: 0..3
  const int e    = blockIdx.x * 16 + wib * 4 + es;

  const float4 a = *(const float4*)(edge_attr + e * EDIM + dg * 4);
  float d[LL];
#pragma unroll
  for (int l = 0; l < LL; ++l) {
    const float4 ev = *(const float4*)(edge_vector + l * EDIM + dg * 4);
    d[l] = a.x * ev.x + a.y * ev.y + a.z * ev.z + a.w * ev.w;
  }
#pragma unroll
  for (int s = 1; s <= 8; s <<= 1) {
#pragma unroll
    for (int l = 0; l < LL; ++l) d[l] += __shfl_xor(d[l], s, 64);
  }
  if (dg < LL) {
    const float dv = (dg == 0) ? d[0] : (dg == 1) ? d[1] : (dg == 2) ? d[2]
                   : (dg == 3) ? d[3] : d[4];
    dotsT[dg * EE + e] = (_Float16)dv;
  }
}

// Kernel 2: persistent, 16 pairs/thread, indices in registers.
// __launch_bounds__(1024, 4): 16 waves/CU = 4 waves/EU -> VGPR cap 128, so
// adr[80]+sum[16] stay in registers (R6 spilled at the default 64-VGPR cap).
__global__ __launch_bounds__(1024, 4) void pairs_kernel(
    const int* __restrict__ ept,
    const _Float16* __restrict__ dotsT,
    float* __restrict__ out) {
  __shared__ __align__(16) unsigned short tab[EE + 8];  // 128 KB + sentinel
  const int tid = blockIdx.x * 1024 + threadIdx.x;      // 0..262143

  // ---- Load 80 indices (4 groups x 5 int4), convert to LDS byte addrs. ----
  int adr[80];          // slot (pair k, l) at adr[k*5+l]; invalid -> EE*2 (sentinel)
  unsigned cp0 = 0u, cp1 = 0u;  // packed 4-bit valid counts, pairs 0..7 / 8..15
#pragma unroll
  for (int g = 0; g < 4; ++g) {
    const size_t gid = (size_t)g * TPK2 + (size_t)tid;  // 4-pair group id
    const int4* p = (const int4*)(ept + gid * 20);
#pragma unroll
    for (int q = 0; q < 5; ++q) {
      const int4 v = p[q];
#pragma unroll
      for (int jj = 0; jj < 4; ++jj) {
        const int si = q * 4 + jj;                 // 0..19 within group
        const int k  = g * 4 + si / 5;             // pair 0..15 (compile-time)
        const int id = (jj == 0) ? v.x : (jj == 1) ? v.y : (jj == 2) ? v.z : v.w;
        adr[g * 20 + si] = (id < 0) ? (EE * 2) : (id * 2);
        const unsigned m = (id >= 0) ? 1u : 0u;
        if (k < 8) cp0 += m << ((k & 7) * 4); else cp1 += m << ((k & 7) * 4);
      }
    }
  }

  float sum[16];
#pragma unroll
  for (int k = 0; k < 16; ++k) sum[k] = 0.f;

  const char* tabb = (const char*)tab;
  if (threadIdx.x == 0) tab[EE] = 0;  // fp16 +0.0 sentinel (outside staged range)

  // ---- 5 passes: stage plane l (128 KB), gather slots with that l. ----
#pragma unroll
  for (int l = 0; l < LL; ++l) {
    __syncthreads();  // prev pass reads done (and sentinel visible on l==0)
    const float4* src = (const float4*)(dotsT + (size_t)l * EE);
    float4* dst = (float4*)tab;
#pragma unroll
    for (int r = 0; r < 8; ++r)
      dst[r * 1024 + threadIdx.x] = src[r * 1024 + threadIdx.x];
    __syncthreads();
#pragma unroll
    for (int k = 0; k < 16; ++k)
      sum[k] += (float)*(const _Float16*)(tabb + adr[k * 5 + l]);
  }

  // ---- Finalize: divide by count, coalesced float4 stores. ----
#pragma unroll
  for (int g = 0; g < 4; ++g) {
    const size_t gid = (size_t)g * TPK2 + (size_t)tid;
    float rr[4];
#pragma unroll
    for (int j = 0; j < 4; ++j) {
      const int k = g * 4 + j;
      const unsigned cnt = (((k < 8) ? cp0 : cp1) >> ((k & 7) * 4)) & 15u;
      rr[j] = sum[k] / ((float)cnt + 1e-10f);  // cnt==0 -> sum==0 -> 0
    }
    ((float4*)out)[gid] = make_float4(rr[0], rr[1], rr[2], rr[3]);
  }
}

extern "C" void kernel_launch(void* const* d_in, const int* in_sizes, int n_in,
                              void* d_out, int out_size, void* d_ws, size_t ws_size,
                              hipStream_t stream) {
  // d_in order: x(unused), edge_attr, edge_vector, edge_paths_tensor, edge_paths_length(unused)
  const float* edge_attr   = (const float*)d_in[1];
  const float* edge_vector = (const float*)d_in[2];
  const int*   ept         = (const int*)d_in[3];
  float* out = (float*)d_out;
  _Float16* dotsT = (_Float16*)d_ws;  // L x E fp16 = 640 KB scratch

  dots_kernel<<<EE / 16, 256, 0, stream>>>(edge_attr, edge_vector, dotsT);

  // Persistent gather kernel: 256 WGs x 1024 threads, 1 WG/CU (128 KB LDS).
  pairs_kernel<<<256, 1024, 0, stream>>>(ept, dotsT, out);
}